// Round 7
// baseline (24575.601 us; speedup 1.0000x reference)
//
#include <hip/hip_runtime.h>
#include <hip/hip_bf16.h>

#define B_  512
#define T_  512
#define FS_ 64
#define FC_ 32
#define H_  256
#define APAD 272   // empirically best (R4: 1.26e7 conflicts vs 7.55e7 at 264)

// ws layout (bf16 element offsets)
#define WS_REC0 0        // [32 ft][8 ks][64 lane][8]   even ft = Wg_h, odd = Wrec
#define WS_REC1 131072
#define WS_X1P  262144   // [32][8][64][8]              even ft = Win1, odd = Wg_x1
#define WS_X0S  393216   // [32][2][64][8]              even ft = Win0, odd = Wg_x0
#define WS_X0C  425984   // [32][1][64][8]              even ft = Win0c, odd = Wg_x0c

typedef __attribute__((ext_vector_type(8))) short bfrag;
typedef __attribute__((ext_vector_type(4))) float ffrag;

__device__ __forceinline__ ffrag mfma16(bfrag a, bfrag b, ffrag c) {
    return __builtin_amdgcn_mfma_f32_16x16x32_bf16(a, b, c, 0, 0, 0);
}
__device__ __forceinline__ float fast_tanh(float x) {
    float e = __builtin_amdgcn_exp2f(x * 2.8853901817f);   // exp(2x), inf-safe
    return 1.f - 2.f * __builtin_amdgcn_rcpf(e + 1.f);
}
// LDS-only barrier: drains LDS but leaves global loads in flight -> weight
// prefetch survives across rounds (m97 barrier-drain lesson).
__device__ __forceinline__ void bar_lds() {
    asm volatile("s_waitcnt lgkmcnt(0)\n\ts_barrier" ::: "memory");
}

// ---------------- prepack: fp32 weights -> bf16 MFMA B-fragments ----------------
__global__ __launch_bounds__(256) void prepack_kernel(
    const float* __restrict__ Win0, const float* __restrict__ Wrec0, const float* __restrict__ Wg0,
    const float* __restrict__ Win1, const float* __restrict__ Wrec1, const float* __restrict__ Wg1,
    __hip_bfloat16* __restrict__ ws)
{
    int g = blockIdx.x * 256 + threadIdx.x;
    if (g >= 55296) return;
    int lane = g & 63;
    int frag = g >> 6;               // 0..863
    int lm = lane & 15, qq = lane >> 4;
    const float* src;
    int dstoff;
    if (frag < 256) {
        int f = frag, ft = f >> 3, ks = f & 7;
        int n = (ft >> 1) * 16 + lm, kk = ks * 32 + qq * 8;
        src = (ft & 1) ? (Wrec0 + n * 256 + kk) : (Wg0 + n * 352 + 96 + kk);
        dstoff = WS_REC0 + (f * 64 + lane) * 8;
    } else if (frag < 512) {
        int f = frag - 256, ft = f >> 3, ks = f & 7;
        int n = (ft >> 1) * 16 + lm, kk = ks * 32 + qq * 8;
        src = (ft & 1) ? (Wrec1 + n * 256 + kk) : (Wg1 + n * 512 + 256 + kk);
        dstoff = WS_REC1 + (f * 64 + lane) * 8;
    } else if (frag < 768) {
        int f = frag - 512, ft = f >> 3, ks = f & 7;
        int n = (ft >> 1) * 16 + lm, kk = ks * 32 + qq * 8;
        src = (ft & 1) ? (Wg1 + n * 512 + kk) : (Win1 + n * 256 + kk);
        dstoff = WS_X1P + (f * 64 + lane) * 8;
    } else if (frag < 832) {
        int f = frag - 768, ft = f >> 1, ks = f & 1;
        int n = (ft >> 1) * 16 + lm, kk = ks * 32 + qq * 8;
        src = (ft & 1) ? (Wg0 + n * 352 + kk) : (Win0 + n * 96 + kk);
        dstoff = WS_X0S + (f * 64 + lane) * 8;
    } else {
        int f = frag - 832, ft = f;
        int n = (ft >> 1) * 16 + lm, kk = qq * 8;
        src = (ft & 1) ? (Wg0 + n * 352 + 64 + kk) : (Win0 + n * 96 + 64 + kk);
        dstoff = WS_X0C + (f * 64 + lane) * 8;
    }
    __hip_bfloat16* d = ws + dstoff;
#pragma unroll
    for (int j = 0; j < 8; j++) d[j] = __float2bfloat16(src[j]);
}

// ---------------- main persistent kernel: 32 WGs x 16 batch rows ----------------
__global__ __launch_bounds__(1024, 4) void lnn_main(
    const float* __restrict__ seq, const float* __restrict__ ctx,
    const float* __restrict__ tau0, const float* __restrict__ bg0,
    const float* __restrict__ lng0, const float* __restrict__ lnb0,
    const float* __restrict__ tau1, const float* __restrict__ bg1,
    const float* __restrict__ lng1, const float* __restrict__ lnb1,
    const float* __restrict__ cW1, const float* __restrict__ cb1,
    const float* __restrict__ cW2, const float* __restrict__ cb2,
    const __hip_bfloat16* __restrict__ ws, float* __restrict__ out)
{
    __shared__ __align__(16) float h0[16][260];
    __shared__ __align__(16) float h1[16][260];
    __shared__ __align__(16) float hn[16][260];
    __shared__ __align__(16) __hip_bfloat16 abf0[2][16][APAD];
    __shared__ __align__(16) __hip_bfloat16 abf1[2][16][APAD];
    __shared__ __align__(16) __hip_bfloat16 xsb[16][80];
    __shared__ __align__(16) float lnw[2][256], lnbv[2][256];

    const int tid  = threadIdx.x;
    const int wave = tid >> 6, lane = tid & 63;
    const int qq   = lane >> 4, lm = lane & 15;
    const int brow = blockIdx.x * 16;
    const int col  = wave * 16 + lm;

    for (int e = tid; e < 16 * 260; e += 1024) { ((float*)h0)[e] = 0.f; ((float*)h1)[e] = 0.f; }
    for (int e = tid; e < 2 * 16 * APAD; e += 1024) {
        ((__hip_bfloat16*)abf0)[e] = __float2bfloat16(0.f);
        ((__hip_bfloat16*)abf1)[e] = __float2bfloat16(0.f);
    }
    for (int c = tid; c < 256; c += 1024) {
        lnw[0][c] = lng0[c]; lnw[1][c] = lng1[c];
        lnbv[0][c] = lnb0[c]; lnbv[1][c] = lnb1[c];
    }
    float rtp[2], bgr[2];
    {
        float t0v = tau0[col], t1v = tau1[col];
        float sp0 = fmaxf(t0v, 0.f) + logf(1.f + __expf(-fabsf(t0v)));
        float sp1 = fmaxf(t1v, 0.f) + logf(1.f + __expf(-fabsf(t1v)));
        rtp[0] = 1.f / (sp0 + 1.f);
        rtp[1] = 1.f / (sp1 + 1.f);
        bgr[0] = bg0[col]; bgr[1] = bg1[col];
    }
    for (int e = tid; e < 16 * FC_; e += 1024) {
        int r = e >> 5, c = e & 31;
        xsb[r][c] = __float2bfloat16(ctx[(brow + r) * FC_ + c]);
    }
    __syncthreads();
    float xcw[4], xcg[4];
    {
        bfrag a = *(const bfrag*)&xsb[lm][qq * 8];
        ffrag zw = {0.f, 0.f, 0.f, 0.f}, zg = {0.f, 0.f, 0.f, 0.f};
        bfrag bw  = *(const bfrag*)(ws + WS_X0C + ((2 * wave) * 64 + lane) * 8);
        bfrag bgf = *(const bfrag*)(ws + WS_X0C + ((2 * wave + 1) * 64 + lane) * 8);
        zw = mfma16(a, bw, zw);
        zg = mfma16(a, bgf, zg);
#pragma unroll
        for (int r = 0; r < 4; r++) { xcw[r] = zw[r]; xcg[r] = zg[r]; }
    }
    __syncthreads();

    // ---- pipeline state (loop-carried registers) ----
    bfrag cg[8], cr[8];          // current layer's rec/gate B-frag cache (VGPRs)
    bfrag xpw[8], xpg[8];        // x1 projection staging (parked in AGPRs)
    float xwin[4], xgate[4];
    float hbase[4], hh[4], ksum[4];
    float seqv;

    auto fillrec = [&](const __hip_bfloat16* __restrict__ rp) {
#pragma unroll
        for (int ks = 0; ks < 8; ks++) {
            cg[ks] = *(const bfrag*)(rp + ((16 * wave + ks) * 64 + lane) * 8);
            cr[ks] = *(const bfrag*)(rp + ((16 * wave + 8 + ks) * 64 + lane) * 8);
        }
    };
    auto pinrec = [&]() {
#pragma unroll
        for (int ks = 0; ks < 8; ks++) {
            asm volatile("" : "+v"(cg[ks]));
            asm volatile("" : "+v"(cr[ks]));
        }
    };
    // extra: 1 = xp fill (issued 3.5 rounds ahead of x1proj)
    //        2 = rec0(t+1) fill
    //        3 = rec1 fill (right after rec0's last MFMA use, 2.5 rounds ahead)
    auto deriv = [&](const __hip_bfloat16 (*Ar)[APAD], __hip_bfloat16 (*Aw)[APAD],
                     int d, float rtpl, int extra) {
        ffrag ag = {0.f, 0.f, 0.f, 0.f}, ar = {0.f, 0.f, 0.f, 0.f};
#pragma unroll
        for (int ks = 0; ks < 8; ks++) {
            bfrag a = *(const bfrag*)&Ar[lm][ks * 32 + qq * 8];
            ag = mfma16(a, cg[ks], ag);
            ar = mfma16(a, cr[ks], ar);
        }
        if (extra == 1) {
#pragma unroll
            for (int ks = 0; ks < 8; ks++) {
                xpw[ks] = *(const bfrag*)(ws + WS_X1P + ((16 * wave + ks) * 64 + lane) * 8);
                xpg[ks] = *(const bfrag*)(ws + WS_X1P + ((16 * wave + 8 + ks) * 64 + lane) * 8);
            }
        } else if (extra == 2) {
            fillrec(ws + WS_REC0);
        } else if (extra == 3) {
            fillrec(ws + WS_REC1);
        }
        float wsm = (d == 1 || d == 2) ? 2.f : 1.f;
        float an  = (d < 2) ? 0.5f : 1.f;
#pragma unroll
        for (int r = 0; r < 4; r++) {
            float t  = fast_tanh(ag[r] + xgate[r]);
            float t2 = t * t;
            // sigmoid(t) on t in (-1,1): odd series, err <= 2.1e-4
            float g  = 0.5f + t * (0.25f + t2 * (-(1.f / 48.f) + t2 * (1.f / 480.f)));
            float kd = xwin[r] - hh[r] * rtpl + g * ar[r];
            ksum[r] += wsm * kd;
            if (d < 3) {
                float hhn = hbase[r] + an * kd;
                hh[r] = hhn;
                Aw[qq * 4 + r][col] = __float2bfloat16(hhn);
            } else {
                hn[qq * 4 + r][col] = hbase[r] + ksum[r] * (1.f / 6.f);
            }
        }
    };
    auto lnorm = [&](float (*hbuf)[260], __hip_bfloat16 (*A0)[APAD], int l) {
        int r = wave, c0 = lane * 4;
        float4 vv = *(const float4*)&hn[r][c0];
        float v[4] = {vv.x, vv.y, vv.z, vv.w};
        float s  = v[0] + v[1] + v[2] + v[3];
        float s2 = v[0]*v[0] + v[1]*v[1] + v[2]*v[2] + v[3]*v[3];
#pragma unroll
        for (int m = 1; m <= 32; m <<= 1) {
            s  += __shfl_xor(s, m, 64);
            s2 += __shfl_xor(s2, m, 64);
        }
        float mean = s * (1.f / 256.f);
        float var  = s2 * (1.f / 256.f) - mean * mean;
        float rs   = __builtin_amdgcn_rsqf(var + 1e-5f);
        float4 lw = *(const float4*)&lnw[l][c0];
        float4 lb = *(const float4*)&lnbv[l][c0];
        float hv[4];
        __hip_bfloat16 hb[4];
        hv[0] = fast_tanh((v[0] - mean) * rs * lw.x + lb.x);
        hv[1] = fast_tanh((v[1] - mean) * rs * lw.y + lb.y);
        hv[2] = fast_tanh((v[2] - mean) * rs * lw.z + lb.z);
        hv[3] = fast_tanh((v[3] - mean) * rs * lw.w + lb.w);
#pragma unroll
        for (int j = 0; j < 4; j++) hb[j] = __float2bfloat16(hv[j]);
        *(float4*)&hbuf[r][c0] = (float4){hv[0], hv[1], hv[2], hv[3]};
        *(uint2*)&A0[r][c0] = *(uint2*)hb;
    };

    fillrec(ws + WS_REC0);                                   // rec0 for t=0
    seqv = seq[((size_t)(brow + wave) * T_ + 0) * FS_ + lane];

#pragma unroll 1
    for (int t = 0; t < T_; t++) {
        xsb[wave][lane] = __float2bfloat16(seqv);
        bar_lds();
        // ---- ROUND A: x0 projection + L0 deriv0 ----
        {
            bfrag b0w[2], b0g[2];
#pragma unroll
            for (int ks = 0; ks < 2; ks++) {
                b0w[ks] = *(const bfrag*)(ws + WS_X0S + ((4 * wave + ks) * 64 + lane) * 8);
                b0g[ks] = *(const bfrag*)(ws + WS_X0S + ((4 * wave + 2 + ks) * 64 + lane) * 8);
            }
            pinrec();   // rec0 (prefetched at L1-deriv3 of t-1 / pre-loop)
            ffrag zw, zg;
#pragma unroll
            for (int r = 0; r < 4; r++) { zw[r] = xcw[r]; zg[r] = xcg[r] + bgr[0]; }
#pragma unroll
            for (int ks = 0; ks < 2; ks++) {
                bfrag a = *(const bfrag*)&xsb[lm][ks * 32 + qq * 8];
                zw = mfma16(a, b0w[ks], zw);
                zg = mfma16(a, b0g[ks], zg);
            }
#pragma unroll
            for (int r = 0; r < 4; r++) { xwin[r] = zw[r]; xgate[r] = zg[r]; }
#pragma unroll
            for (int r = 0; r < 4; r++) {
                float v = h0[qq * 4 + r][col];
                hbase[r] = v; hh[r] = v; ksum[r] = 0.f;
            }
            int tn = (t + 1 < T_) ? t + 1 : t;
            seqv = seq[((size_t)(brow + wave) * T_ + tn) * FS_ + lane];   // prefetch
            deriv(abf0[0], abf0[1], 0, rtp[0], 0);
        }
        bar_lds();
        deriv(abf0[1], abf0[0], 1, rtp[0], 1);   // + xp fill (3.5 rounds ahead)
        bar_lds();
        deriv(abf0[0], abf0[1], 2, rtp[0], 0);
        bar_lds();
        deriv(abf0[1], abf0[0], 3, rtp[0], 3);   // + rec1 fill (WAR after rec0 last use)
        bar_lds();
        lnorm(h0, abf0[0], 0);
        bar_lds();
        // ---- x1 projection (xp from AGPRs), then L1 deriv0 ----
        {
#pragma unroll
            for (int ks = 0; ks < 8; ks++) {
                asm volatile("" : "+a"(xpw[ks]));
                asm volatile("" : "+a"(xpg[ks]));
            }
            ffrag zw = {0.f, 0.f, 0.f, 0.f}, zg;
#pragma unroll
            for (int r = 0; r < 4; r++) zg[r] = bgr[1];
#pragma unroll
            for (int ks = 0; ks < 8; ks++) {
                bfrag a = *(const bfrag*)&abf0[0][lm][ks * 32 + qq * 8];
                zw = mfma16(a, xpw[ks], zw);
                zg = mfma16(a, xpg[ks], zg);
            }
#pragma unroll
            for (int r = 0; r < 4; r++) { xwin[r] = zw[r]; xgate[r] = zg[r]; }
#pragma unroll
            for (int r = 0; r < 4; r++) {
                float v = h1[qq * 4 + r][col];
                hbase[r] = v; hh[r] = v; ksum[r] = 0.f;
            }
            pinrec();   // rec1 (filled at L0-deriv3)
            deriv(abf1[0], abf1[1], 0, rtp[1], 0);
        }
        bar_lds();
        deriv(abf1[1], abf1[0], 1, rtp[1], 0);
        bar_lds();
        deriv(abf1[0], abf1[1], 2, rtp[1], 0);
        bar_lds();
        deriv(abf1[1], abf1[0], 3, rtp[1], 2);   // + rec0(t+1) fill
        bar_lds();
        lnorm(h1, abf1[0], 1);
        // no barrier here: LN1's writes (h1, abf1[0]) are next read >=5 barriers later
    }

    __syncthreads();
    // ---- head: hid = relu(h1 @ cW1^T + cb1); out = hid @ cW2^T + cb2 ----
    {
        int r = wave;
        float acc0 = cb1[lane], acc1 = cb1[lane + 64];
        const float* w0 = cW1 + (size_t)lane * H_;
        const float* w1 = cW1 + (size_t)(lane + 64) * H_;
        for (int k = 0; k < H_; k += 4) {
            float4 hv = *(const float4*)&h1[r][k];
            acc0 += hv.x * w0[k] + hv.y * w0[k+1] + hv.z * w0[k+2] + hv.w * w0[k+3];
            acc1 += hv.x * w1[k] + hv.y * w1[k+1] + hv.z * w1[k+2] + hv.w * w1[k+3];
        }
        __syncthreads();
        hn[r][lane]      = fmaxf(acc0, 0.f);
        hn[r][lane + 64] = fmaxf(acc1, 0.f);
    }
    __syncthreads();
    if (tid < 16) {
        float acc = cb2[0];
        for (int k = 0; k < 128; k++) acc += hn[tid][k] * cW2[k];
        out[brow + tid] = acc;
    }
}

extern "C" void kernel_launch(void* const* d_in, const int* in_sizes, int n_in,
                              void* d_out, int out_size, void* d_ws, size_t ws_size,
                              hipStream_t stream) {
    const float* seq   = (const float*)d_in[0];
    const float* ctx   = (const float*)d_in[1];
    const float* tau0  = (const float*)d_in[2];
    const float* Win0  = (const float*)d_in[3];
    const float* Wrec0 = (const float*)d_in[4];
    const float* Wg0   = (const float*)d_in[5];
    const float* bg0   = (const float*)d_in[6];
    const float* lng0  = (const float*)d_in[7];
    const float* lnb0  = (const float*)d_in[8];
    const float* tau1  = (const float*)d_in[9];
    const float* Win1  = (const float*)d_in[10];
    const float* Wrec1 = (const float*)d_in[11];
    const float* Wg1   = (const float*)d_in[12];
    const float* bg1   = (const float*)d_in[13];
    const float* lng1  = (const float*)d_in[14];
    const float* lnb1  = (const float*)d_in[15];
    const float* cW1   = (const float*)d_in[16];
    const float* cb1   = (const float*)d_in[17];
    const float* cW2   = (const float*)d_in[18];
    const float* cb2   = (const float*)d_in[19];
    __hip_bfloat16* ws = (__hip_bfloat16*)d_ws;

    hipLaunchKernelGGL(prepack_kernel, dim3(216), dim3(256), 0, stream,
                       Win0, Wrec0, Wg0, Win1, Wrec1, Wg1, ws);
    hipLaunchKernelGGL(lnn_main, dim3(32), dim3(1024), 0, stream,
                       seq, ctx, tau0, bg0, lng0, lnb0, tau1, bg1, lng1, lnb1,
                       cW1, cb1, cW2, cb2, ws, (float*)d_out);
}

// Round 8
// 18782.256 us; speedup vs baseline: 1.3084x; 1.3084x over previous
//
#include <hip/hip_runtime.h>
#include <hip/hip_bf16.h>

#define B_  512
#define T_  512
#define FS_ 64
#define FC_ 32
#define H_  256
#define APAD 272   // empirically best (R4: 1.26e7 conflicts vs 7.55e7 at 264)

// ws layout (bf16 element offsets)
#define WS_REC0 0        // [32 ft][8 ks][64 lane][8]   even ft = Wg_h, odd = Wrec
#define WS_REC1 131072
#define WS_X1P  262144   // [32][8][64][8]              even ft = Win1, odd = Wg_x1
#define WS_X0S  393216   // [32][2][64][8]              even ft = Win0, odd = Wg_x0
#define WS_X0C  425984   // [32][1][64][8]              even ft = Win0c, odd = Wg_x0c

typedef __attribute__((ext_vector_type(8))) short bfrag;
typedef __attribute__((ext_vector_type(4))) float ffrag;

__device__ __forceinline__ ffrag mfma16(bfrag a, bfrag b, ffrag c) {
    return __builtin_amdgcn_mfma_f32_16x16x32_bf16(a, b, c, 0, 0, 0);
}
__device__ __forceinline__ float fast_tanh(float x) {
    float e = __builtin_amdgcn_exp2f(x * 2.8853901817f);   // exp(2x), inf-safe
    return 1.f - 2.f * __builtin_amdgcn_rcpf(e + 1.f);
}
// LDS-only barrier: drains LDS but leaves global loads in flight -> weight
// prefetch survives across rounds (m97 barrier-drain lesson).
__device__ __forceinline__ void bar_lds() {
    asm volatile("s_waitcnt lgkmcnt(0)\n\ts_barrier" ::: "memory");
}

// ---------------- prepack: fp32 weights -> bf16 MFMA B-fragments ----------------
__global__ __launch_bounds__(256) void prepack_kernel(
    const float* __restrict__ Win0, const float* __restrict__ Wrec0, const float* __restrict__ Wg0,
    const float* __restrict__ Win1, const float* __restrict__ Wrec1, const float* __restrict__ Wg1,
    __hip_bfloat16* __restrict__ ws)
{
    int g = blockIdx.x * 256 + threadIdx.x;
    if (g >= 55296) return;
    int lane = g & 63;
    int frag = g >> 6;               // 0..863
    int lm = lane & 15, qq = lane >> 4;
    const float* src;
    int dstoff;
    if (frag < 256) {
        int f = frag, ft = f >> 3, ks = f & 7;
        int n = (ft >> 1) * 16 + lm, kk = ks * 32 + qq * 8;
        src = (ft & 1) ? (Wrec0 + n * 256 + kk) : (Wg0 + n * 352 + 96 + kk);
        dstoff = WS_REC0 + (f * 64 + lane) * 8;
    } else if (frag < 512) {
        int f = frag - 256, ft = f >> 3, ks = f & 7;
        int n = (ft >> 1) * 16 + lm, kk = ks * 32 + qq * 8;
        src = (ft & 1) ? (Wrec1 + n * 256 + kk) : (Wg1 + n * 512 + 256 + kk);
        dstoff = WS_REC1 + (f * 64 + lane) * 8;
    } else if (frag < 768) {
        int f = frag - 512, ft = f >> 3, ks = f & 7;
        int n = (ft >> 1) * 16 + lm, kk = ks * 32 + qq * 8;
        src = (ft & 1) ? (Wg1 + n * 512 + kk) : (Win1 + n * 256 + kk);
        dstoff = WS_X1P + (f * 64 + lane) * 8;
    } else if (frag < 832) {
        int f = frag - 768, ft = f >> 1, ks = f & 1;
        int n = (ft >> 1) * 16 + lm, kk = ks * 32 + qq * 8;
        src = (ft & 1) ? (Wg0 + n * 352 + kk) : (Win0 + n * 96 + kk);
        dstoff = WS_X0S + (f * 64 + lane) * 8;
    } else {
        int f = frag - 832, ft = f;
        int n = (ft >> 1) * 16 + lm, kk = qq * 8;
        src = (ft & 1) ? (Wg0 + n * 352 + 64 + kk) : (Win0 + n * 96 + 64 + kk);
        dstoff = WS_X0C + (f * 64 + lane) * 8;
    }
    __hip_bfloat16* d = ws + dstoff;
#pragma unroll
    for (int j = 0; j < 8; j++) d[j] = __float2bfloat16(src[j]);
}

// ---------------- main persistent kernel: 32 WGs x 16 batch rows ----------------
// R8 = R6 schedule (the proven 13.5 ms liveness pattern: at most ONE 64-reg
// prefetch in flight while the other 64-reg cache is live) + two deltas:
//   (a) rec1 fill moved to LN0-round start (lead 0.2 -> 1.2 rounds; cg/cr is
//       dead there, xp is the only live 64-reg block -> same peak as R6's d3)
//   (b) end-of-loop barrier dropped (LN1 writes next read >=6 barriers later)
// R7 post-mortem: xp fill at d1 made xp+cg/cr live together for 3 rounds ->
// 128+work regs -> scratch spill (WRITE_SIZE 14MB -> 5.4GB). Don't do that.
__global__ __launch_bounds__(1024, 4) void lnn_main(
    const float* __restrict__ seq, const float* __restrict__ ctx,
    const float* __restrict__ tau0, const float* __restrict__ bg0,
    const float* __restrict__ lng0, const float* __restrict__ lnb0,
    const float* __restrict__ tau1, const float* __restrict__ bg1,
    const float* __restrict__ lng1, const float* __restrict__ lnb1,
    const float* __restrict__ cW1, const float* __restrict__ cb1,
    const float* __restrict__ cW2, const float* __restrict__ cb2,
    const __hip_bfloat16* __restrict__ ws, float* __restrict__ out)
{
    __shared__ __align__(16) float h0[16][260];
    __shared__ __align__(16) float h1[16][260];
    __shared__ __align__(16) float hn[16][260];
    __shared__ __align__(16) __hip_bfloat16 abf0[2][16][APAD];
    __shared__ __align__(16) __hip_bfloat16 abf1[2][16][APAD];
    __shared__ __align__(16) __hip_bfloat16 xsb[16][80];
    __shared__ __align__(16) float lnw[2][256], lnbv[2][256];

    const int tid  = threadIdx.x;
    const int wave = tid >> 6, lane = tid & 63;
    const int qq   = lane >> 4, lm = lane & 15;
    const int brow = blockIdx.x * 16;
    const int col  = wave * 16 + lm;

    for (int e = tid; e < 16 * 260; e += 1024) { ((float*)h0)[e] = 0.f; ((float*)h1)[e] = 0.f; }
    for (int e = tid; e < 2 * 16 * APAD; e += 1024) {
        ((__hip_bfloat16*)abf0)[e] = __float2bfloat16(0.f);
        ((__hip_bfloat16*)abf1)[e] = __float2bfloat16(0.f);
    }
    for (int c = tid; c < 256; c += 1024) {
        lnw[0][c] = lng0[c]; lnw[1][c] = lng1[c];
        lnbv[0][c] = lnb0[c]; lnbv[1][c] = lnb1[c];
    }
    float rtp[2], bgr[2];
    {
        float t0v = tau0[col], t1v = tau1[col];
        float sp0 = fmaxf(t0v, 0.f) + logf(1.f + __expf(-fabsf(t0v)));
        float sp1 = fmaxf(t1v, 0.f) + logf(1.f + __expf(-fabsf(t1v)));
        rtp[0] = 1.f / (sp0 + 1.f);
        rtp[1] = 1.f / (sp1 + 1.f);
        bgr[0] = bg0[col]; bgr[1] = bg1[col];
    }
    for (int e = tid; e < 16 * FC_; e += 1024) {
        int r = e >> 5, c = e & 31;
        xsb[r][c] = __float2bfloat16(ctx[(brow + r) * FC_ + c]);
    }
    __syncthreads();
    float xcw[4], xcg[4];
    {
        bfrag a = *(const bfrag*)&xsb[lm][qq * 8];
        ffrag zw = {0.f, 0.f, 0.f, 0.f}, zg = {0.f, 0.f, 0.f, 0.f};
        bfrag bw  = *(const bfrag*)(ws + WS_X0C + ((2 * wave) * 64 + lane) * 8);
        bfrag bgf = *(const bfrag*)(ws + WS_X0C + ((2 * wave + 1) * 64 + lane) * 8);
        zw = mfma16(a, bw, zw);
        zg = mfma16(a, bgf, zg);
#pragma unroll
        for (int r = 0; r < 4; r++) { xcw[r] = zw[r]; xcg[r] = zg[r]; }
    }
    __syncthreads();

    // ---- pipeline state (loop-carried registers) ----
    bfrag cg[8], cr[8];          // current layer's rec/gate B-frag cache
    bfrag xpw[8], xpg[8];        // x1 projection staging
    float xwin[4], xgate[4];
    float hbase[4], hh[4], ksum[4];
    float seqv;

    auto fillrec = [&](const __hip_bfloat16* __restrict__ rp) {
#pragma unroll
        for (int ks = 0; ks < 8; ks++) {
            cg[ks] = *(const bfrag*)(rp + ((16 * wave + ks) * 64 + lane) * 8);
            cr[ks] = *(const bfrag*)(rp + ((16 * wave + 8 + ks) * 64 + lane) * 8);
        }
    };
    auto pinrec = [&]() {
#pragma unroll
        for (int ks = 0; ks < 8; ks++) {
            asm volatile("" : "+v"(cg[ks]));
            asm volatile("" : "+v"(cr[ks]));
        }
    };
    // extra: 1 = xp fill (L0-d3: cg/cr about to die -> brief 128-reg peak, proven OK)
    //        2 = rec0(t+1) fill (L1-d3)
    auto deriv = [&](const __hip_bfloat16 (*Ar)[APAD], __hip_bfloat16 (*Aw)[APAD],
                     int d, float rtpl, int extra) {
        ffrag ag = {0.f, 0.f, 0.f, 0.f}, ar = {0.f, 0.f, 0.f, 0.f};
#pragma unroll
        for (int ks = 0; ks < 8; ks++) {
            bfrag a = *(const bfrag*)&Ar[lm][ks * 32 + qq * 8];
            ag = mfma16(a, cg[ks], ag);
            ar = mfma16(a, cr[ks], ar);
        }
        if (extra == 1) {
#pragma unroll
            for (int ks = 0; ks < 8; ks++) {
                xpw[ks] = *(const bfrag*)(ws + WS_X1P + ((16 * wave + ks) * 64 + lane) * 8);
                xpg[ks] = *(const bfrag*)(ws + WS_X1P + ((16 * wave + 8 + ks) * 64 + lane) * 8);
            }
        } else if (extra == 2) {
            fillrec(ws + WS_REC0);
        }
        float wsm = (d == 1 || d == 2) ? 2.f : 1.f;
        float an  = (d < 2) ? 0.5f : 1.f;
#pragma unroll
        for (int r = 0; r < 4; r++) {
            float t  = fast_tanh(ag[r] + xgate[r]);
            float t2 = t * t;
            // sigmoid(t) on t in (-1,1): odd series, err <= 2.1e-4
            float g  = 0.5f + t * (0.25f + t2 * (-(1.f / 48.f) + t2 * (1.f / 480.f)));
            float kd = xwin[r] - hh[r] * rtpl + g * ar[r];
            ksum[r] += wsm * kd;
            if (d < 3) {
                float hhn = hbase[r] + an * kd;
                hh[r] = hhn;
                Aw[qq * 4 + r][col] = __float2bfloat16(hhn);
            } else {
                hn[qq * 4 + r][col] = hbase[r] + ksum[r] * (1.f / 6.f);
            }
        }
    };
    auto lnorm = [&](float (*hbuf)[260], __hip_bfloat16 (*A0)[APAD], int l) {
        int r = wave, c0 = lane * 4;
        float4 vv = *(const float4*)&hn[r][c0];
        float v[4] = {vv.x, vv.y, vv.z, vv.w};
        float s  = v[0] + v[1] + v[2] + v[3];
        float s2 = v[0]*v[0] + v[1]*v[1] + v[2]*v[2] + v[3]*v[3];
#pragma unroll
        for (int m = 1; m <= 32; m <<= 1) {
            s  += __shfl_xor(s, m, 64);
            s2 += __shfl_xor(s2, m, 64);
        }
        float mean = s * (1.f / 256.f);
        float var  = s2 * (1.f / 256.f) - mean * mean;
        float rs   = __builtin_amdgcn_rsqf(var + 1e-5f);
        float4 lw = *(const float4*)&lnw[l][c0];
        float4 lb = *(const float4*)&lnbv[l][c0];
        float hv[4];
        __hip_bfloat16 hb[4];
        hv[0] = fast_tanh((v[0] - mean) * rs * lw.x + lb.x);
        hv[1] = fast_tanh((v[1] - mean) * rs * lw.y + lb.y);
        hv[2] = fast_tanh((v[2] - mean) * rs * lw.z + lb.z);
        hv[3] = fast_tanh((v[3] - mean) * rs * lw.w + lb.w);
#pragma unroll
        for (int j = 0; j < 4; j++) hb[j] = __float2bfloat16(hv[j]);
        *(float4*)&hbuf[r][c0] = (float4){hv[0], hv[1], hv[2], hv[3]};
        *(uint2*)&A0[r][c0] = *(uint2*)hb;
    };

    fillrec(ws + WS_REC0);                                   // rec0 for t=0
    seqv = seq[((size_t)(brow + wave) * T_ + 0) * FS_ + lane];

#pragma unroll 1
    for (int t = 0; t < T_; t++) {
        xsb[wave][lane] = __float2bfloat16(seqv);
        bar_lds();
        // ---- ROUND A: x0 projection + L0 deriv0 ----
        {
            bfrag b0w[2], b0g[2];
#pragma unroll
            for (int ks = 0; ks < 2; ks++) {
                b0w[ks] = *(const bfrag*)(ws + WS_X0S + ((4 * wave + ks) * 64 + lane) * 8);
                b0g[ks] = *(const bfrag*)(ws + WS_X0S + ((4 * wave + 2 + ks) * 64 + lane) * 8);
            }
            pinrec();   // rec0 (prefetched at L1-deriv3 of t-1 / pre-loop)
            ffrag zw, zg;
#pragma unroll
            for (int r = 0; r < 4; r++) { zw[r] = xcw[r]; zg[r] = xcg[r] + bgr[0]; }
#pragma unroll
            for (int ks = 0; ks < 2; ks++) {
                bfrag a = *(const bfrag*)&xsb[lm][ks * 32 + qq * 8];
                zw = mfma16(a, b0w[ks], zw);
                zg = mfma16(a, b0g[ks], zg);
            }
#pragma unroll
            for (int r = 0; r < 4; r++) { xwin[r] = zw[r]; xgate[r] = zg[r]; }
#pragma unroll
            for (int r = 0; r < 4; r++) {
                float v = h0[qq * 4 + r][col];
                hbase[r] = v; hh[r] = v; ksum[r] = 0.f;
            }
            int tn = (t + 1 < T_) ? t + 1 : t;
            seqv = seq[((size_t)(brow + wave) * T_ + tn) * FS_ + lane];   // prefetch
            deriv(abf0[0], abf0[1], 0, rtp[0], 0);
        }
        bar_lds();
        deriv(abf0[1], abf0[0], 1, rtp[0], 0);
        bar_lds();
        deriv(abf0[0], abf0[1], 2, rtp[0], 0);
        bar_lds();
        deriv(abf0[1], abf0[0], 3, rtp[0], 1);   // + xp fill (cg/cr dies this round)
        bar_lds();
        fillrec(ws + WS_REC1);                   // rec1 fill, 1.2 rounds ahead of use
        lnorm(h0, abf0[0], 0);
        bar_lds();
        // ---- x1 projection (consume xp), then L1 deriv0 ----
        {
#pragma unroll
            for (int ks = 0; ks < 8; ks++) {
                asm volatile("" : "+v"(xpw[ks]));
                asm volatile("" : "+v"(xpg[ks]));
            }
            ffrag zw = {0.f, 0.f, 0.f, 0.f}, zg;
#pragma unroll
            for (int r = 0; r < 4; r++) zg[r] = bgr[1];
#pragma unroll
            for (int ks = 0; ks < 8; ks++) {
                bfrag a = *(const bfrag*)&abf0[0][lm][ks * 32 + qq * 8];
                zw = mfma16(a, xpw[ks], zw);
                zg = mfma16(a, xpg[ks], zg);
            }
#pragma unroll
            for (int r = 0; r < 4; r++) { xwin[r] = zw[r]; xgate[r] = zg[r]; }
#pragma unroll
            for (int r = 0; r < 4; r++) {
                float v = h1[qq * 4 + r][col];
                hbase[r] = v; hh[r] = v; ksum[r] = 0.f;
            }
            pinrec();   // rec1 (filled at LN0 round)
            deriv(abf1[0], abf1[1], 0, rtp[1], 0);
        }
        bar_lds();
        deriv(abf1[1], abf1[0], 1, rtp[1], 0);
        bar_lds();
        deriv(abf1[0], abf1[1], 2, rtp[1], 0);
        bar_lds();
        deriv(abf1[1], abf1[0], 3, rtp[1], 2);   // + rec0(t+1) fill
        bar_lds();
        lnorm(h1, abf1[0], 1);
        // no barrier: LN1's writes (h1, abf1[0]) next read >=6 barriers later
    }

    __syncthreads();
    // ---- head: hid = relu(h1 @ cW1^T + cb1); out = hid @ cW2^T + cb2 ----
    {
        int r = wave;
        float acc0 = cb1[lane], acc1 = cb1[lane + 64];
        const float* w0 = cW1 + (size_t)lane * H_;
        const float* w1 = cW1 + (size_t)(lane + 64) * H_;
        for (int k = 0; k < H_; k += 4) {
            float4 hv = *(const float4*)&h1[r][k];
            acc0 += hv.x * w0[k] + hv.y * w0[k+1] + hv.z * w0[k+2] + hv.w * w0[k+3];
            acc1 += hv.x * w1[k] + hv.y * w1[k+1] + hv.z * w1[k+2] + hv.w * w1[k+3];
        }
        __syncthreads();
        hn[r][lane]      = fmaxf(acc0, 0.f);
        hn[r][lane + 64] = fmaxf(acc1, 0.f);
    }
    __syncthreads();
    if (tid < 16) {
        float acc = cb2[0];
        for (int k = 0; k < 128; k++) acc += hn[tid][k] * cW2[k];
        out[brow + tid] = acc;
    }
}

extern "C" void kernel_launch(void* const* d_in, const int* in_sizes, int n_in,
                              void* d_out, int out_size, void* d_ws, size_t ws_size,
                              hipStream_t stream) {
    const float* seq   = (const float*)d_in[0];
    const float* ctx   = (const float*)d_in[1];
    const float* tau0  = (const float*)d_in[2];
    const float* Win0  = (const float*)d_in[3];
    const float* Wrec0 = (const float*)d_in[4];
    const float* Wg0   = (const float*)d_in[5];
    const float* bg0   = (const float*)d_in[6];
    const float* lng0  = (const float*)d_in[7];
    const float* lnb0  = (const float*)d_in[8];
    const float* tau1  = (const float*)d_in[9];
    const float* Win1  = (const float*)d_in[10];
    const float* Wrec1 = (const float*)d_in[11];
    const float* Wg1   = (const float*)d_in[12];
    const float* bg1   = (const float*)d_in[13];
    const float* lng1  = (const float*)d_in[14];
    const float* lnb1  = (const float*)d_in[15];
    const float* cW1   = (const float*)d_in[16];
    const float* cb1   = (const float*)d_in[17];
    const float* cW2   = (const float*)d_in[18];
    const float* cb2   = (const float*)d_in[19];
    __hip_bfloat16* ws = (__hip_bfloat16*)d_ws;

    hipLaunchKernelGGL(prepack_kernel, dim3(216), dim3(256), 0, stream,
                       Win0, Wrec0, Wg0, Win1, Wrec1, Wg1, ws);
    hipLaunchKernelGGL(lnn_main, dim3(32), dim3(1024), 0, stream,
                       seq, ctx, tau0, bg0, lng0, lnb0, tau1, bg1, lng1, lnb1,
                       cW1, cb1, cW2, cb2, ws, (float*)d_out);
}

// Round 9
// 7896.387 us; speedup vs baseline: 3.1123x; 2.3786x over previous
//
#include <hip/hip_runtime.h>
#include <hip/hip_bf16.h>

#define T_  512
#define FS_ 64
#define FC_ 32
#define H_  256
#define APAD 272

// ws layout (bf16 element offsets)
#define WS_REC0 0        // [32 ft][8 ks][64 lane][8]   even ft = Wg_h, odd = Wrec
#define WS_REC1 131072
#define WS_X1P  262144   // [32][8][64][8]              even ft = Win1, odd = Wg_x1
#define WS_X0S  393216   // [32][2][64][8]              even ft = Win0, odd = Wg_x0
#define WS_X0C  425984   // [32][1][64][8]
#define WS_MBOX 458752   // [32 tiles][2 parity][16*256] bf16 h0 mailbox
#define WS_FLAG_BYTE ((458752 + 262144) * 2)   // 128 ints: pub[64], ack[64]

typedef __attribute__((ext_vector_type(8))) short bfrag;
typedef __attribute__((ext_vector_type(4))) float ffrag;

__device__ __forceinline__ ffrag mfma16(bfrag a, bfrag b, ffrag c) {
    return __builtin_amdgcn_mfma_f32_16x16x32_bf16(a, b, c, 0, 0, 0);
}
__device__ __forceinline__ float fast_tanh(float x) {
    float e = __builtin_amdgcn_exp2f(x * 2.8853901817f);   // exp(2x), inf-safe
    return 1.f - 2.f * __builtin_amdgcn_rcpf(e + 1.f);
}
__device__ __forceinline__ void bar_lds() {
    asm volatile("s_waitcnt lgkmcnt(0)\n\ts_barrier" ::: "memory");
}

// ---------------- prepack: fp32 weights -> bf16 MFMA B-fragments + flag reset ---
__global__ __launch_bounds__(256) void prepack_kernel(
    const float* __restrict__ Win0, const float* __restrict__ Wrec0, const float* __restrict__ Wg0,
    const float* __restrict__ Win1, const float* __restrict__ Wrec1, const float* __restrict__ Wg1,
    __hip_bfloat16* __restrict__ ws)
{
    int g = blockIdx.x * 256 + threadIdx.x;
    if (g < 128) ((int*)((char*)ws + WS_FLAG_BYTE))[g] = 0;   // pub/ack flags: reset every launch
    if (g >= 55296) return;
    int lane = g & 63;
    int frag = g >> 6;
    int lm = lane & 15, qq = lane >> 4;
    const float* src;
    int dstoff;
    if (frag < 256) {
        int f = frag, ft = f >> 3, ks = f & 7;
        int n = (ft >> 1) * 16 + lm, kk = ks * 32 + qq * 8;
        src = (ft & 1) ? (Wrec0 + n * 256 + kk) : (Wg0 + n * 352 + 96 + kk);
        dstoff = WS_REC0 + (f * 64 + lane) * 8;
    } else if (frag < 512) {
        int f = frag - 256, ft = f >> 3, ks = f & 7;
        int n = (ft >> 1) * 16 + lm, kk = ks * 32 + qq * 8;
        src = (ft & 1) ? (Wrec1 + n * 256 + kk) : (Wg1 + n * 512 + 256 + kk);
        dstoff = WS_REC1 + (f * 64 + lane) * 8;
    } else if (frag < 768) {
        int f = frag - 512, ft = f >> 3, ks = f & 7;
        int n = (ft >> 1) * 16 + lm, kk = ks * 32 + qq * 8;
        src = (ft & 1) ? (Wg1 + n * 512 + kk) : (Win1 + n * 256 + kk);
        dstoff = WS_X1P + (f * 64 + lane) * 8;
    } else if (frag < 832) {
        int f = frag - 768, ft = f >> 1, ks = f & 1;
        int n = (ft >> 1) * 16 + lm, kk = ks * 32 + qq * 8;
        src = (ft & 1) ? (Wg0 + n * 352 + kk) : (Win0 + n * 96 + kk);
        dstoff = WS_X0S + (f * 64 + lane) * 8;
    } else {
        int f = frag - 832, ft = f;
        int n = (ft >> 1) * 16 + lm, kk = qq * 8;
        src = (ft & 1) ? (Wg0 + n * 352 + 64 + kk) : (Win0 + n * 96 + 64 + kk);
        dstoff = WS_X0C + (f * 64 + lane) * 8;
    }
    __hip_bfloat16* d = ws + dstoff;
#pragma unroll
    for (int j = 0; j < 8; j++) d[j] = __float2bfloat16(src[j]);
}

// ---------------- main: 64 WGs = 32 layer-0 producers + 32 layer-1 consumers ----
// Each WG pins ITS layer's rec weights in registers permanently (fill once).
// A publishes bf16 h0(t) via double-buffered global mailbox (release/acquire,
// device scope); B stages it to LDS, acks, runs layer 1, writes the head.
__global__ __launch_bounds__(1024, 4) void lnn_main(
    const float* __restrict__ seq, const float* __restrict__ ctx,
    const float* __restrict__ tau0, const float* __restrict__ bg0,
    const float* __restrict__ lng0, const float* __restrict__ lnb0,
    const float* __restrict__ tau1, const float* __restrict__ bg1,
    const float* __restrict__ lng1, const float* __restrict__ lnb1,
    const float* __restrict__ cW1, const float* __restrict__ cb1,
    const float* __restrict__ cW2, const float* __restrict__ cb2,
    __hip_bfloat16* __restrict__ ws, float* __restrict__ out)
{
    __shared__ __align__(16) float hbuf[16][260];
    __shared__ __align__(16) float hn[16][260];
    __shared__ __align__(16) __hip_bfloat16 abf[2][16][APAD];
    __shared__ __align__(16) __hip_bfloat16 x1A[16][APAD];     // B: staged h0 tile
    __shared__ __align__(16) __hip_bfloat16 xsb[16][80];       // A: ctx/seq staging
    __shared__ __align__(16) float lnw[256], lnb[256];

    const int tid  = threadIdx.x;
    const int wave = tid >> 6, lane = tid & 63;
    const int qq   = lane >> 4, lm = lane & 15;
    const int bid  = blockIdx.x;
    const int tile = bid & 31, roleB = bid >> 5;
    const int brow = tile * 16;
    const int col  = wave * 16 + lm;

    int* flags = (int*)((char*)ws + WS_FLAG_BYTE);
    int* pubf  = flags + tile * 2;          // [parity]
    int* ackf  = flags + 64 + tile * 2;     // [parity]
    __hip_bfloat16* mb0 = ws + WS_MBOX + tile * 2 * 4096;

    for (int e = tid; e < 16 * 260; e += 1024) ((float*)hbuf)[e] = 0.f;
    for (int e = tid; e < 2 * 16 * APAD; e += 1024)
        ((__hip_bfloat16*)abf)[e] = __float2bfloat16(0.f);
    {
        const float* lg = roleB ? lng1 : lng0;
        const float* lb = roleB ? lnb1 : lnb0;
        for (int c = tid; c < 256; c += 1024) { lnw[c] = lg[c]; lnb[c] = lb[c]; }
    }
    float rtpv, bgrv;
    {
        float tv = roleB ? tau1[col] : tau0[col];
        float sp = fmaxf(tv, 0.f) + logf(1.f + __expf(-fabsf(tv)));
        rtpv = 1.f / (sp + 1.f);
        bgrv = roleB ? bg1[col] : bg0[col];
    }

    // ---- pinned per-layer rec/gate weight cache (filled ONCE, lives forever) ----
    bfrag cg[8], cr[8];
    {
        const __hip_bfloat16* rp = ws + (roleB ? WS_REC1 : WS_REC0);
#pragma unroll
        for (int ks = 0; ks < 8; ks++) {
            cg[ks] = *(const bfrag*)(rp + ((16 * wave + ks) * 64 + lane) * 8);
            cr[ks] = *(const bfrag*)(rp + ((16 * wave + 8 + ks) * 64 + lane) * 8);
        }
    }
    auto pinrec = [&]() {
#pragma unroll
        for (int ks = 0; ks < 8; ks++) {
            asm volatile("" : "+v"(cg[ks]));
            asm volatile("" : "+v"(cr[ks]));
        }
    };

    float xwin[4], xgate[4];
    float hbase[4], hh[4], ksum[4];

    auto deriv = [&](const __hip_bfloat16 (*Ar)[APAD], __hip_bfloat16 (*Aw)[APAD], int d) {
        ffrag ag = {0.f, 0.f, 0.f, 0.f}, ar = {0.f, 0.f, 0.f, 0.f};
#pragma unroll
        for (int ks = 0; ks < 8; ks++) {
            bfrag a = *(const bfrag*)&Ar[lm][ks * 32 + qq * 8];
            ag = mfma16(a, cg[ks], ag);
            ar = mfma16(a, cr[ks], ar);
        }
        float wsm = (d == 1 || d == 2) ? 2.f : 1.f;
        float an  = (d < 2) ? 0.5f : 1.f;
#pragma unroll
        for (int r = 0; r < 4; r++) {
            float t  = fast_tanh(ag[r] + xgate[r]);
            float t2 = t * t;
            float g  = 0.5f + t * (0.25f + t2 * (-(1.f / 48.f) + t2 * (1.f / 480.f)));
            float kd = xwin[r] - hh[r] * rtpv + g * ar[r];
            ksum[r] += wsm * kd;
            if (d < 3) {
                float hhn = hbase[r] + an * kd;
                hh[r] = hhn;
                Aw[qq * 4 + r][col] = __float2bfloat16(hhn);
            } else {
                hn[qq * 4 + r][col] = hbase[r] + ksum[r] * (1.f / 6.f);
            }
        }
    };
    auto loadbase = [&]() {
#pragma unroll
        for (int r = 0; r < 4; r++) {
            float v = hbuf[qq * 4 + r][col];
            hbase[r] = v; hh[r] = v; ksum[r] = 0.f;
        }
    };
    auto lnorm = [&](__hip_bfloat16* mbslot) {
        int r = wave, c0 = lane * 4;
        float4 vv = *(const float4*)&hn[r][c0];
        float v[4] = {vv.x, vv.y, vv.z, vv.w};
        float s  = v[0] + v[1] + v[2] + v[3];
        float s2 = v[0]*v[0] + v[1]*v[1] + v[2]*v[2] + v[3]*v[3];
#pragma unroll
        for (int m = 1; m <= 32; m <<= 1) {
            s  += __shfl_xor(s, m, 64);
            s2 += __shfl_xor(s2, m, 64);
        }
        float mean = s * (1.f / 256.f);
        float var  = s2 * (1.f / 256.f) - mean * mean;
        float rs   = __builtin_amdgcn_rsqf(var + 1e-5f);
        float4 lw = *(const float4*)&lnw[c0];
        float4 lb = *(const float4*)&lnb[c0];
        float hv[4];
        __hip_bfloat16 hb[4];
        hv[0] = fast_tanh((v[0] - mean) * rs * lw.x + lb.x);
        hv[1] = fast_tanh((v[1] - mean) * rs * lw.y + lb.y);
        hv[2] = fast_tanh((v[2] - mean) * rs * lw.z + lb.z);
        hv[3] = fast_tanh((v[3] - mean) * rs * lw.w + lb.w);
#pragma unroll
        for (int j = 0; j < 4; j++) hb[j] = __float2bfloat16(hv[j]);
        *(float4*)&hbuf[r][c0] = (float4){hv[0], hv[1], hv[2], hv[3]};
        *(uint2*)&abf[0][r][c0] = *(uint2*)hb;
        if (mbslot) *(uint2*)&mbslot[r * 256 + c0] = *(uint2*)hb;
    };

    if (!roleB) {
        // =================== role A: layer 0 producer ===================
        for (int e = tid; e < 16 * FC_; e += 1024) {
            int r = e >> 5, c = e & 31;
            xsb[r][c] = __float2bfloat16(ctx[(brow + r) * FC_ + c]);
        }
        __syncthreads();
        float xcw[4], xcg[4];
        {
            bfrag a = *(const bfrag*)&xsb[lm][qq * 8];
            ffrag zw = {0.f, 0.f, 0.f, 0.f}, zg = {0.f, 0.f, 0.f, 0.f};
            bfrag bw  = *(const bfrag*)(ws + WS_X0C + ((2 * wave) * 64 + lane) * 8);
            bfrag bgf = *(const bfrag*)(ws + WS_X0C + ((2 * wave + 1) * 64 + lane) * 8);
            zw = mfma16(a, bw, zw);
            zg = mfma16(a, bgf, zg);
#pragma unroll
            for (int r = 0; r < 4; r++) { xcw[r] = zw[r]; xcg[r] = zg[r]; }
        }
        __syncthreads();
        float seqv = seq[((size_t)(brow + wave) * T_ + 0) * FS_ + lane];

#pragma unroll 1
        for (int t = 0; t < T_; t++) {
            int p = t & 1;
            xsb[wave][lane] = __float2bfloat16(seqv);
            if (tid == 0 && t >= 2) {   // slot p free? (B consumed step t-2 -> ack = t-1)
                int guard = 1 << 27;
                while (__hip_atomic_load(&ackf[p], __ATOMIC_ACQUIRE,
                                         __HIP_MEMORY_SCOPE_AGENT) < t - 1 && --guard) {}
            }
            __syncthreads();
            pinrec();
            {   // x0 projection + d0
                bfrag b0w[2], b0g[2];
#pragma unroll
                for (int ks = 0; ks < 2; ks++) {
                    b0w[ks] = *(const bfrag*)(ws + WS_X0S + ((4 * wave + ks) * 64 + lane) * 8);
                    b0g[ks] = *(const bfrag*)(ws + WS_X0S + ((4 * wave + 2 + ks) * 64 + lane) * 8);
                }
                ffrag zw, zg;
#pragma unroll
                for (int r = 0; r < 4; r++) { zw[r] = xcw[r]; zg[r] = xcg[r] + bgrv; }
#pragma unroll
                for (int ks = 0; ks < 2; ks++) {
                    bfrag a = *(const bfrag*)&xsb[lm][ks * 32 + qq * 8];
                    zw = mfma16(a, b0w[ks], zw);
                    zg = mfma16(a, b0g[ks], zg);
                }
#pragma unroll
                for (int r = 0; r < 4; r++) { xwin[r] = zw[r]; xgate[r] = zg[r]; }
                loadbase();
                int tn = (t + 1 < T_) ? t + 1 : t;
                seqv = seq[((size_t)(brow + wave) * T_ + tn) * FS_ + lane];
                deriv(abf[0], abf[1], 0);
            }
            bar_lds(); deriv(abf[1], abf[0], 1);
            bar_lds(); deriv(abf[0], abf[1], 2);
            bar_lds(); deriv(abf[1], abf[0], 3);
            bar_lds();
            lnorm(mb0 + p * 4096);
            __threadfence();
            __syncthreads();
            if (tid == 0)
                __hip_atomic_store(&pubf[p], t + 1, __ATOMIC_RELEASE,
                                   __HIP_MEMORY_SCOPE_AGENT);
        }
        return;
    }

    // =================== role B: layer 1 consumer + head ===================
#pragma unroll 1
    for (int t = 0; t < T_; t++) {
        int p = t & 1;
        if (tid == 0) {   // wait for A's publish of step t
            int guard = 1 << 27;
            while (__hip_atomic_load(&pubf[p], __ATOMIC_ACQUIRE,
                                     __HIP_MEMORY_SCOPE_AGENT) < t + 1 && --guard) {}
        }
        __syncthreads();
        {   // stage mailbox -> LDS (1024 thr x 8 B = 8 KB, coalesced)
            int r = tid >> 6, c0 = (tid & 63) * 4;
            uint2 v = *(const uint2*)&mb0[p * 4096 + r * 256 + c0];
            *(uint2*)&x1A[r][c0] = v;
        }
        __syncthreads();
        if (tid == 0)
            __hip_atomic_store(&ackf[p], t + 1, __ATOMIC_RELEASE,
                               __HIP_MEMORY_SCOPE_AGENT);
        pinrec();
        {   // x1 projection: stream x1p from L2, 2-chunk software pipeline + d0
            const __hip_bfloat16* xp = ws + WS_X1P;
            ffrag zw = {0.f, 0.f, 0.f, 0.f}, zg;
#pragma unroll
            for (int r = 0; r < 4; r++) zg[r] = bgrv;
            bfrag w0 = *(const bfrag*)(xp + ((16 * wave + 0) * 64 + lane) * 8);
            bfrag w1 = *(const bfrag*)(xp + ((16 * wave + 1) * 64 + lane) * 8);
            bfrag g0 = *(const bfrag*)(xp + ((16 * wave + 8) * 64 + lane) * 8);
            bfrag g1 = *(const bfrag*)(xp + ((16 * wave + 9) * 64 + lane) * 8);
#pragma unroll
            for (int c = 0; c < 4; c++) {
                int ks = 2 * c;
                bfrag w2, w3, g2, g3;
                if (c < 3) {
                    w2 = *(const bfrag*)(xp + ((16 * wave + ks + 2) * 64 + lane) * 8);
                    w3 = *(const bfrag*)(xp + ((16 * wave + ks + 3) * 64 + lane) * 8);
                    g2 = *(const bfrag*)(xp + ((16 * wave + 8 + ks + 2) * 64 + lane) * 8);
                    g3 = *(const bfrag*)(xp + ((16 * wave + 8 + ks + 3) * 64 + lane) * 8);
                }
                bfrag a0 = *(const bfrag*)&x1A[lm][ks * 32 + qq * 8];
                bfrag a1 = *(const bfrag*)&x1A[lm][(ks + 1) * 32 + qq * 8];
                zw = mfma16(a0, w0, zw); zw = mfma16(a1, w1, zw);
                zg = mfma16(a0, g0, zg); zg = mfma16(a1, g1, zg);
                w0 = w2; w1 = w3; g0 = g2; g1 = g3;
            }
#pragma unroll
            for (int r = 0; r < 4; r++) { xwin[r] = zw[r]; xgate[r] = zg[r]; }
            loadbase();
            deriv(abf[0], abf[1], 0);
        }
        bar_lds(); deriv(abf[1], abf[0], 1);
        bar_lds(); deriv(abf[0], abf[1], 2);
        bar_lds(); deriv(abf[1], abf[0], 3);
        bar_lds();
        lnorm(nullptr);
        __syncthreads();
    }

    // ---- head: hid = relu(h1 @ cW1^T + cb1); out = hid @ cW2^T + cb2 ----
    {
        int r = wave;
        float acc0 = cb1[lane], acc1 = cb1[lane + 64];
        const float* w0 = cW1 + (size_t)lane * H_;
        const float* w1 = cW1 + (size_t)(lane + 64) * H_;
        for (int k = 0; k < H_; k += 4) {
            float4 hv = *(const float4*)&hbuf[r][k];
            acc0 += hv.x * w0[k] + hv.y * w0[k+1] + hv.z * w0[k+2] + hv.w * w0[k+3];
            acc1 += hv.x * w1[k] + hv.y * w1[k+1] + hv.z * w1[k+2] + hv.w * w1[k+3];
        }
        __syncthreads();
        hn[r][lane]      = fmaxf(acc0, 0.f);
        hn[r][lane + 64] = fmaxf(acc1, 0.f);
    }
    __syncthreads();
    if (tid < 16) {
        float acc = cb2[0];
        for (int k = 0; k < 128; k++) acc += hn[tid][k] * cW2[k];
        out[brow + tid] = acc;
    }
}

extern "C" void kernel_launch(void* const* d_in, const int* in_sizes, int n_in,
                              void* d_out, int out_size, void* d_ws, size_t ws_size,
                              hipStream_t stream) {
    const float* seq   = (const float*)d_in[0];
    const float* ctx   = (const float*)d_in[1];
    const float* tau0  = (const float*)d_in[2];
    const float* Win0  = (const float*)d_in[3];
    const float* Wrec0 = (const float*)d_in[4];
    const float* Wg0   = (const float*)d_in[5];
    const float* bg0   = (const float*)d_in[6];
    const float* lng0  = (const float*)d_in[7];
    const float* lnb0  = (const float*)d_in[8];
    const float* tau1  = (const float*)d_in[9];
    const float* Win1  = (const float*)d_in[10];
    const float* Wrec1 = (const float*)d_in[11];
    const float* Wg1   = (const float*)d_in[12];
    const float* bg1   = (const float*)d_in[13];
    const float* lng1  = (const float*)d_in[14];
    const float* lnb1  = (const float*)d_in[15];
    const float* cW1   = (const float*)d_in[16];
    const float* cb1   = (const float*)d_in[17];
    const float* cW2   = (const float*)d_in[18];
    const float* cb2   = (const float*)d_in[19];
    __hip_bfloat16* ws = (__hip_bfloat16*)d_ws;

    hipLaunchKernelGGL(prepack_kernel, dim3(216), dim3(256), 0, stream,
                       Win0, Wrec0, Wg0, Win1, Wrec1, Wg1, ws);
    hipLaunchKernelGGL(lnn_main, dim3(64), dim3(1024), 0, stream,
                       seq, ctx, tau0, bg0, lng0, lnb0, tau1, bg1, lng1, lnb1,
                       cW1, cb1, cW2, cb2, ws, (float*)d_out);
}